// Round 8
// baseline (164.336 us; speedup 1.0000x reference)
//
#include <hip/hip_runtime.h>
#include <math.h>

#define NNODES 50000
#define NEDGES 800000
#define HIDDEN 128
#define NH 8
#define HD 16
#define CAP 64            // max in-degree; Binomial(8e5,1/5e4) max ~35, P(>=64) negligible
#define NPART 8           // dst partitions ~ XCDs (blockIdx&7 round-robins XCDs)
#define PART_SZ 6250      // 50000/8
#define SCAT_BPP 128      // blocks per partition
#define QKV_WAVES 6250    // 3125 row-bands x 2 halves

typedef __bf16 bf16x8 __attribute__((ext_vector_type(8)));
typedef float  f32x4  __attribute__((ext_vector_type(4)));

// RNE float -> bf16 bits
__device__ inline unsigned short f2b(float f) {
    unsigned u = __float_as_uint(f);
    unsigned r = (u + 0x7fffu + ((u >> 16) & 1u)) >> 16;
    return (unsigned short)r;
}

// load 8 consecutive fp32 -> one bf16x8 MFMA fragment
__device__ inline bf16x8 ld_a8(const float* __restrict__ p) {
    float4 a = *(const float4*)p;
    float4 b = *(const float4*)(p + 4);
    bf16x8 r;
    r[0] = (__bf16)a.x; r[1] = (__bf16)a.y; r[2] = (__bf16)a.z; r[3] = (__bf16)a.w;
    r[4] = (__bf16)b.x; r[5] = (__bf16)b.y; r[6] = (__bf16)b.z; r[7] = (__bf16)b.w;
    return r;
}

// ---- pack weights into MFMA fragment order ----
// slot s (0..95: qkv, 96..127: Wo): P[s*512 + lane*8 + j] =
//   W[colin*128 + c*32 + (lane>>4)*8 + j],  colin = ct*16 + (lane&15), s = ct*4+c
__global__ __launch_bounds__(256)
void pack_w(const float* __restrict__ Wq, const float* __restrict__ Wk,
            const float* __restrict__ Wv, const float* __restrict__ Wo,
            unsigned short* __restrict__ Pqkv, unsigned short* __restrict__ Po)
{
    const int s = blockIdx.x * 4 + (threadIdx.x >> 6);   // 0..127
    const int lane = threadIdx.x & 63;
    const float* W; unsigned short* P; int ct, c;
    if (s < 96) { ct = s >> 2; c = s & 3;
        W = (ct < 8) ? Wq : (ct < 16) ? Wk : Wv;
        P = Pqkv + (size_t)s * 512;
        ct &= 7;
    } else { int t = s - 96; ct = t >> 2; c = t & 3; W = Wo; P = Po + (size_t)t * 512; }
    const int colin = ct * 16 + (lane & 15);
    const int k0 = c * 32 + (lane >> 4) * 8;
    const float* sp = W + (size_t)colin * 128 + k0;
    unsigned short v[8];
#pragma unroll
    for (int j = 0; j < 8; ++j) v[j] = f2b(sp[j]);
    uint4 o;
    o.x = (unsigned)v[0] | ((unsigned)v[1] << 16);
    o.y = (unsigned)v[2] | ((unsigned)v[3] << 16);
    o.z = (unsigned)v[4] | ((unsigned)v[5] << 16);
    o.w = (unsigned)v[6] | ((unsigned)v[7] << 16);
    *(uint4*)(P + lane * 8) = o;
}

// ---- XCD-partitioned edge bucketing ----
// partition p = blockIdx&7 owns dst in [p*PART_SZ, (p+1)*PART_SZ); each
// partition grid-strides the full edge list -> bucket slice stays in one
// XCD's L2, partial-sector writes coalesce before writeback.
__global__ __launch_bounds__(256)
void scatter_kernel(const int* __restrict__ src, const int* __restrict__ dst,
                    int* __restrict__ cnt, int* __restrict__ bucket)
{
    const int part = blockIdx.x & (NPART - 1);
    const int blk  = blockIdx.x >> 3;          // 0..SCAT_BPP-1
    const int lo = part * PART_SZ, hi = lo + PART_SZ;
    for (int e = blk * 256 + threadIdx.x; e < NEDGES; e += SCAT_BPP * 256) {
        const int d = dst[e];
        if (d >= lo && d < hi) {
            const int pos = atomicAdd(&cnt[d], 1);
            if (pos < CAP) bucket[d * CAP + pos] = src[e];
        }
    }
}

// ---- QKV projection: swapped MFMA, vectorized stores, no LDS ----
// wave w: band = w>>1 (16 rows), half = w&1 (12 col tiles). Swapped
// mfma(W,x) -> lane (ar,kg) holds C[row0+ar][ct*16+kg*4+{0..3}].
// KVb pairwise layout: K[2l..2l+1] at n*256+4l, V[2l..2l+1] at n*256+4l+2.
__global__ __launch_bounds__(256)
void qkv_mfma(const float* __restrict__ x, const unsigned short* __restrict__ Pqkv,
              const float* __restrict__ bq, const float* __restrict__ bk,
              const float* __restrict__ bv,
              unsigned short* __restrict__ Qb, unsigned short* __restrict__ KVb)
{
    const int w = blockIdx.x * 4 + (threadIdx.x >> 6);
    if (w >= QKV_WAVES) return;
    const int lane = threadIdx.x & 63;
    const int band = w >> 1, half = w & 1;
    const int row0 = band * 16;
    const int ar = lane & 15, kg = lane >> 4;

    const float* ap = x + (size_t)(row0 + ar) * 128 + kg * 8;
    const bf16x8 a0 = ld_a8(ap);
    const bf16x8 a1 = ld_a8(ap + 32);
    const bf16x8 a2 = ld_a8(ap + 64);
    const bf16x8 a3 = ld_a8(ap + 96);

#pragma unroll
    for (int t = 0; t < 12; ++t) {
        const int ct = half * 12 + t;
        const unsigned short* wb = Pqkv + (size_t)(ct * 4) * 512 + lane * 8;
        bf16x8 w0 = *(const bf16x8*)(wb);
        bf16x8 w1 = *(const bf16x8*)(wb + 512);
        bf16x8 w2 = *(const bf16x8*)(wb + 1024);
        bf16x8 w3 = *(const bf16x8*)(wb + 1536);

        f32x4 acc = {0.f, 0.f, 0.f, 0.f};
        acc = __builtin_amdgcn_mfma_f32_16x16x32_bf16(w0, a0, acc, 0, 0, 0);
        acc = __builtin_amdgcn_mfma_f32_16x16x32_bf16(w1, a1, acc, 0, 0, 0);
        acc = __builtin_amdgcn_mfma_f32_16x16x32_bf16(w2, a2, acc, 0, 0, 0);
        acc = __builtin_amdgcn_mfma_f32_16x16x32_bf16(w3, a3, acc, 0, 0, 0);

        const int sel = ct >> 3;              // 0=Q 1=K 2=V
        const int colbase = (ct & 7) * 16 + kg * 4;
        const float* bias = (sel == 0) ? bq : (sel == 1) ? bk : bv;
        const float4 b4 = *(const float4*)(bias + colbase);
        const float v0 = acc[0] + b4.x, v1 = acc[1] + b4.y;
        const float v2 = acc[2] + b4.z, v3 = acc[3] + b4.w;
        if (sel == 0) {
            ushort4 q4 = { f2b(v0), f2b(v1), f2b(v2), f2b(v3) };
            *(ushort4*)(Qb + (size_t)(row0 + ar) * 128 + colbase) = q4;
        } else {
            const int koff = (sel == 2) ? 2 : 0;
            unsigned short* p = KVb + (size_t)(row0 + ar) * 256 + colbase * 2 + koff;
            *(unsigned*)(p)     = (unsigned)f2b(v0) | ((unsigned)f2b(v1) << 16);
            *(unsigned*)(p + 4) = (unsigned)f2b(v2) | ((unsigned)f2b(v3) << 16);
        }
    }
}

// ---- Fused score + online softmax + aggregation, 1 wave / node ----
__global__ __launch_bounds__(256)
void fused_attn_kernel(const unsigned short* __restrict__ Qb,
                       const unsigned short* __restrict__ KVb,
                       const int* __restrict__ cnt, const int* __restrict__ bucket,
                       unsigned short* __restrict__ accumb)
{
    const int wave = threadIdx.x >> 6;
    const int lane = threadIdx.x & 63;
    const int n = blockIdx.x * 4 + wave;
    if (n >= NNODES) return;

    int deg = cnt[n];
    deg = deg > CAP ? CAP : deg;
    const int mysrc = (lane < deg) ? bucket[n * CAP + lane] : 0;

    const unsigned qw = *(const unsigned*)(Qb + (size_t)n * HIDDEN + lane * 2);
    const float qx = __uint_as_float(qw << 16);
    const float qy = __uint_as_float(qw & 0xffff0000u);

    float m = -INFINITY, s = 0.f, ox = 0.f, oy = 0.f;

    uint2 kv0 = make_uint2(0, 0), kv1 = make_uint2(0, 0);
    if (deg > 0) { const int s0 = __shfl(mysrc, 0);
                   kv0 = *(const uint2*)(KVb + (size_t)s0 * 256 + lane * 4); }
    if (deg > 1) { const int s1 = __shfl(mysrc, 1);
                   kv1 = *(const uint2*)(KVb + (size_t)s1 * 256 + lane * 4); }

    for (int i = 0; i < deg; ++i) {
        const uint2 cur = kv0;
        kv0 = kv1;
        if (i + 2 < deg) {
            const int s2 = __shfl(mysrc, i + 2);
            kv1 = *(const uint2*)(KVb + (size_t)s2 * 256 + lane * 4);
        }
        const float kx = __uint_as_float(cur.x << 16);
        const float ky = __uint_as_float(cur.x & 0xffff0000u);
        const float vx = __uint_as_float(cur.y << 16);
        const float vy = __uint_as_float(cur.y & 0xffff0000u);
        float part = qx * kx + qy * ky;
        part += __shfl_xor(part, 1);
        part += __shfl_xor(part, 2);
        part += __shfl_xor(part, 4);   // 8 lanes of the head hold the dot
        const float score = part * 0.25f;   // D^-0.5
        const float d = score - m;
        const float e = __expf(-fabsf(d));
        const bool nmx = d > 0.f;
        const float scale = nmx ? e : 1.f;
        const float p     = nmx ? 1.f : e;
        m = nmx ? score : m;
        s  = s  * scale + p;
        ox = ox * scale + p * vx;
        oy = oy * scale + p * vy;
    }
    const float inv = 1.f / (s + 1e-12f);
    ushort2 ob = { f2b(ox * inv), f2b(oy * inv) };
    *(ushort2*)(accumb + (size_t)n * HIDDEN + lane * 2) = ob;
}

// ---- output projection: swapped MFMA, float4 stores ----
__global__ __launch_bounds__(256)
void outproj_mfma(const unsigned short* __restrict__ accumb, const unsigned short* __restrict__ Po,
                  const float* __restrict__ bo, float* __restrict__ out)
{
    const int band = blockIdx.x * 4 + (threadIdx.x >> 6);
    if (band >= 3125) return;
    const int lane = threadIdx.x & 63;
    const int row0 = band * 16;
    const int ar = lane & 15, kg = lane >> 4;

    const unsigned short* ab = accumb + (size_t)(row0 + ar) * 128 + kg * 8;
    const bf16x8 a0 = *(const bf16x8*)(ab);
    const bf16x8 a1 = *(const bf16x8*)(ab + 32);
    const bf16x8 a2 = *(const bf16x8*)(ab + 64);
    const bf16x8 a3 = *(const bf16x8*)(ab + 96);

#pragma unroll
    for (int t = 0; t < 8; ++t) {
        const unsigned short* wb = Po + (size_t)(t * 4) * 512 + lane * 8;
        bf16x8 w0 = *(const bf16x8*)(wb);
        bf16x8 w1 = *(const bf16x8*)(wb + 512);
        bf16x8 w2 = *(const bf16x8*)(wb + 1024);
        bf16x8 w3 = *(const bf16x8*)(wb + 1536);

        f32x4 acc = {0.f, 0.f, 0.f, 0.f};
        acc = __builtin_amdgcn_mfma_f32_16x16x32_bf16(w0, a0, acc, 0, 0, 0);
        acc = __builtin_amdgcn_mfma_f32_16x16x32_bf16(w1, a1, acc, 0, 0, 0);
        acc = __builtin_amdgcn_mfma_f32_16x16x32_bf16(w2, a2, acc, 0, 0, 0);
        acc = __builtin_amdgcn_mfma_f32_16x16x32_bf16(w3, a3, acc, 0, 0, 0);

        const int colbase = t * 16 + kg * 4;
        const float4 b4 = *(const float4*)(bo + colbase);
        float4 o4 = { acc[0] + b4.x, acc[1] + b4.y, acc[2] + b4.z, acc[3] + b4.w };
        *(float4*)(out + (size_t)(row0 + ar) * 128 + colbase) = o4;
    }
}

extern "C" void kernel_launch(void* const* d_in, const int* in_sizes, int n_in,
                              void* d_out, int out_size, void* d_ws, size_t ws_size,
                              hipStream_t stream) {
    const float* x  = (const float*)d_in[0];
    const int*   ei = (const int*)d_in[1];      // (2, E) int32: [0]=src, [1]=dst
    const int*   src = ei;
    const int*   dst = ei + NEDGES;
    const float* Wq = (const float*)d_in[3];
    const float* bq = (const float*)d_in[4];
    const float* Wk = (const float*)d_in[5];
    const float* bk = (const float*)d_in[6];
    const float* Wv = (const float*)d_in[7];
    const float* bv = (const float*)d_in[8];
    const float* Wo = (const float*)d_in[9];
    const float* bo = (const float*)d_in[10];
    float* out = (float*)d_out;

    // workspace layout (all offsets 16B-aligned)
    char* ws = (char*)d_ws;
    size_t off = 0;
    const size_t sz_nhb = (size_t)NNODES * HIDDEN * sizeof(unsigned short); // 12.8 MB
    unsigned short* Qb     = (unsigned short*)(ws + off); off += sz_nhb;
    unsigned short* KVb    = (unsigned short*)(ws + off); off += 2 * sz_nhb;
    unsigned short* accumb = (unsigned short*)(ws + off); off += sz_nhb;
    unsigned short* Pqkv   = (unsigned short*)(ws + off); off += 96 * 512 * sizeof(unsigned short);
    unsigned short* Po     = (unsigned short*)(ws + off); off += 32 * 512 * sizeof(unsigned short);
    int*            cnt    = (int*)(ws + off);            off += (size_t)NNODES * sizeof(int);
    int*            bucket = (int*)(ws + off);            off += (size_t)NNODES * CAP * sizeof(int);

    hipMemsetAsync(cnt, 0, (size_t)NNODES * sizeof(int), stream);

    pack_w<<<32, 256, 0, stream>>>(Wq, Wk, Wv, Wo, Pqkv, Po);

    scatter_kernel<<<NPART * SCAT_BPP, 256, 0, stream>>>(src, dst, cnt, bucket);

    qkv_mfma<<<(QKV_WAVES + 3) / 4, 256, 0, stream>>>(x, Pqkv, bq, bk, bv, Qb, KVb);

    fused_attn_kernel<<<(NNODES + 3) / 4, 256, 0, stream>>>(Qb, KVb, cnt, bucket, accumb);

    outproj_mfma<<<782, 256, 0, stream>>>(accumb, Po, bo, out);
}

// Round 9
// 147.863 us; speedup vs baseline: 1.1114x; 1.1114x over previous
//
#include <hip/hip_runtime.h>
#include <math.h>

#define NNODES 50000
#define NEDGES 800000
#define HIDDEN 128
#define NH 8
#define HD 16
#define CAP 64            // max in-degree; Binomial(8e5,1/5e4) max ~35, P(>=64) negligible
#define NPART 8           // dst partitions ~ XCDs
#define PART_SZ 6250      // 50000/8
#define SCAT_BPP 128      // blocks per partition
#define QKV_WAVES 6250    // 3125 row-bands x 2 halves

typedef __bf16 bf16x8 __attribute__((ext_vector_type(8)));
typedef float  f32x4  __attribute__((ext_vector_type(4)));

// RNE float -> bf16 bits
__device__ inline unsigned short f2b(float f) {
    unsigned u = __float_as_uint(f);
    unsigned r = (u + 0x7fffu + ((u >> 16) & 1u)) >> 16;
    return (unsigned short)r;
}

// load 8 consecutive fp32 -> one bf16x8 MFMA fragment
__device__ inline bf16x8 ld_a8(const float* __restrict__ p) {
    float4 a = *(const float4*)p;
    float4 b = *(const float4*)(p + 4);
    bf16x8 r;
    r[0] = (__bf16)a.x; r[1] = (__bf16)a.y; r[2] = (__bf16)a.z; r[3] = (__bf16)a.w;
    r[4] = (__bf16)b.x; r[5] = (__bf16)b.y; r[6] = (__bf16)b.z; r[7] = (__bf16)b.w;
    return r;
}

// ---- pack weights into MFMA fragment order ----
// slot s (0..95: qkv, 96..127: Wo): P[s*512 + lane*8 + j] =
//   W[colin*128 + c*32 + (lane>>4)*8 + j],  colin = ct*16 + (lane&15), s = ct*4+c
__global__ __launch_bounds__(256)
void pack_w(const float* __restrict__ Wq, const float* __restrict__ Wk,
            const float* __restrict__ Wv, const float* __restrict__ Wo,
            unsigned short* __restrict__ Pqkv, unsigned short* __restrict__ Po)
{
    const int s = blockIdx.x * 4 + (threadIdx.x >> 6);   // 0..127
    const int lane = threadIdx.x & 63;
    const float* W; unsigned short* P; int ct, c;
    if (s < 96) { ct = s >> 2; c = s & 3;
        W = (ct < 8) ? Wq : (ct < 16) ? Wk : Wv;
        P = Pqkv + (size_t)s * 512;
        ct &= 7;
    } else { int t = s - 96; ct = t >> 2; c = t & 3; W = Wo; P = Po + (size_t)t * 512; }
    const int colin = ct * 16 + (lane & 15);
    const int k0 = c * 32 + (lane >> 4) * 8;
    const float* sp = W + (size_t)colin * 128 + k0;
    unsigned short v[8];
#pragma unroll
    for (int j = 0; j < 8; ++j) v[j] = f2b(sp[j]);
    uint4 o;
    o.x = (unsigned)v[0] | ((unsigned)v[1] << 16);
    o.y = (unsigned)v[2] | ((unsigned)v[3] << 16);
    o.z = (unsigned)v[4] | ((unsigned)v[5] << 16);
    o.w = (unsigned)v[6] | ((unsigned)v[7] << 16);
    *(uint4*)(P + lane * 8) = o;
}

// ---- XCD-partitioned edge bucketing ----
__global__ __launch_bounds__(256)
void scatter_kernel(const int* __restrict__ src, const int* __restrict__ dst,
                    int* __restrict__ cnt, int* __restrict__ bucket)
{
    const int part = blockIdx.x & (NPART - 1);
    const int blk  = blockIdx.x >> 3;          // 0..SCAT_BPP-1
    const int lo = part * PART_SZ, hi = lo + PART_SZ;
    for (int e = blk * 256 + threadIdx.x; e < NEDGES; e += SCAT_BPP * 256) {
        const int d = dst[e];
        if (d >= lo && d < hi) {
            const int pos = atomicAdd(&cnt[d], 1);
            if (pos < CAP) bucket[d * CAP + pos] = src[e];
        }
    }
}

// ---- QKV projection: non-swapped mfma(x,W), software-pipelined B loads ----
// lane (ar=lane&15, kg=lane>>4) holds C[row0+kg*4+j][ct*16+ar] -> 16 lanes
// store consecutive cols of one row (coalesced segments, no write amp).
// KVb pairwise layout: K[2l..2l+1] at n*256+4l, V[2l..2l+1] at n*256+4l+2.
__global__ __launch_bounds__(256)
void qkv_mfma(const float* __restrict__ x, const unsigned short* __restrict__ Pqkv,
              const float* __restrict__ bq, const float* __restrict__ bk,
              const float* __restrict__ bv,
              unsigned short* __restrict__ Qb, unsigned short* __restrict__ KVb)
{
    const int w = blockIdx.x * 4 + (threadIdx.x >> 6);
    if (w >= QKV_WAVES) return;
    const int lane = threadIdx.x & 63;
    const int band = w >> 1, half = w & 1;
    const int row0 = band * 16;
    const int ar = lane & 15, kg = lane >> 4;

    const float* ap = x + (size_t)(row0 + ar) * 128 + kg * 8;
    const bf16x8 a0 = ld_a8(ap);
    const bf16x8 a1 = ld_a8(ap + 32);
    const bf16x8 a2 = ld_a8(ap + 64);
    const bf16x8 a3 = ld_a8(ap + 96);

    const unsigned short* wp = Pqkv + (size_t)(half * 48) * 512 + lane * 8;
    // prefetch tile 0's B fragments
    bf16x8 nb0 = *(const bf16x8*)(wp);
    bf16x8 nb1 = *(const bf16x8*)(wp + 512);
    bf16x8 nb2 = *(const bf16x8*)(wp + 1024);
    bf16x8 nb3 = *(const bf16x8*)(wp + 1536);

#pragma unroll
    for (int t = 0; t < 12; ++t) {
        const bf16x8 b0 = nb0, b1 = nb1, b2 = nb2, b3 = nb3;
        if (t < 11) {
            const unsigned short* nw = wp + (size_t)(t + 1) * 2048;
            nb0 = *(const bf16x8*)(nw);
            nb1 = *(const bf16x8*)(nw + 512);
            nb2 = *(const bf16x8*)(nw + 1024);
            nb3 = *(const bf16x8*)(nw + 1536);
        }
        f32x4 acc = {0.f, 0.f, 0.f, 0.f};
        acc = __builtin_amdgcn_mfma_f32_16x16x32_bf16(a0, b0, acc, 0, 0, 0);
        acc = __builtin_amdgcn_mfma_f32_16x16x32_bf16(a1, b1, acc, 0, 0, 0);
        acc = __builtin_amdgcn_mfma_f32_16x16x32_bf16(a2, b2, acc, 0, 0, 0);
        acc = __builtin_amdgcn_mfma_f32_16x16x32_bf16(a3, b3, acc, 0, 0, 0);

        const int ct = half * 12 + t;
        const int sel = ct >> 3;              // 0=Q 1=K 2=V
        const int colin = (ct & 7) * 16 + ar;
        if (sel == 0) {
            const float bsc = bq[colin];
#pragma unroll
            for (int j = 0; j < 4; ++j)
                Qb[(size_t)(row0 + kg * 4 + j) * 128 + colin] = f2b(acc[j] + bsc);
        } else {
            const float bsc = (sel == 1) ? bk[colin] : bv[colin];
            const int koff = (sel == 2) ? 2 : 0;
            const int cbase = (colin >> 1) * 4 + (colin & 1) + koff;
#pragma unroll
            for (int j = 0; j < 4; ++j)
                KVb[(size_t)(row0 + kg * 4 + j) * 256 + cbase] = f2b(acc[j] + bsc);
        }
    }
}

// ---- Fused score + online softmax + aggregation, 1 wave / node ----
// pair-processed edges: two independent dot/reduce chains per iteration,
// pair-combined with 1 exp, then one online merge (1 exp) -> 1 exp/edge.
__global__ __launch_bounds__(256)
void fused_attn_kernel(const unsigned short* __restrict__ Qb,
                       const unsigned short* __restrict__ KVb,
                       const int* __restrict__ cnt, const int* __restrict__ bucket,
                       unsigned short* __restrict__ accumb)
{
    const int wave = threadIdx.x >> 6;
    const int lane = threadIdx.x & 63;
    const int n = blockIdx.x * 4 + wave;
    if (n >= NNODES) return;

    int deg = cnt[n];
    deg = deg > CAP ? CAP : deg;
    const int mysrc = (lane < deg) ? bucket[n * CAP + lane] : 0;

    const unsigned short* kvbase = KVb + lane * 4;

    // q pre-scaled by D^-0.5 so dot == score
    const unsigned qw = *(const unsigned*)(Qb + (size_t)n * HIDDEN + lane * 2);
    const float qx = __uint_as_float(qw << 16) * 0.25f;
    const float qy = __uint_as_float(qw & 0xffff0000u) * 0.25f;

    float m = -INFINITY, s = 0.f, ox = 0.f, oy = 0.f;

    // prefetch ring, depth 4
    uint2 kvA = make_uint2(0,0), kvB = kvA, kvC = kvA, kvD = kvA;
    if (deg > 0) kvA = *(const uint2*)(kvbase + ((size_t)__shfl(mysrc, 0) << 8));
    if (deg > 1) kvB = *(const uint2*)(kvbase + ((size_t)__shfl(mysrc, 1) << 8));
    if (deg > 2) kvC = *(const uint2*)(kvbase + ((size_t)__shfl(mysrc, 2) << 8));
    if (deg > 3) kvD = *(const uint2*)(kvbase + ((size_t)__shfl(mysrc, 3) << 8));

    int i = 0;
    for (; i + 2 <= deg; i += 2) {
        const uint2 c0 = kvA, c1 = kvB;
        kvA = kvC; kvB = kvD;
        if (i + 4 < deg) kvC = *(const uint2*)(kvbase + ((size_t)__shfl(mysrc, i + 4) << 8));
        if (i + 5 < deg) kvD = *(const uint2*)(kvbase + ((size_t)__shfl(mysrc, i + 5) << 8));

        // two independent score chains
        float d0 = qx * __uint_as_float(c0.x << 16) + qy * __uint_as_float(c0.x & 0xffff0000u);
        float d1 = qx * __uint_as_float(c1.x << 16) + qy * __uint_as_float(c1.x & 0xffff0000u);
        d0 += __shfl_xor(d0, 1);  d1 += __shfl_xor(d1, 1);
        d0 += __shfl_xor(d0, 2);  d1 += __shfl_xor(d1, 2);
        d0 += __shfl_xor(d0, 4);  d1 += __shfl_xor(d1, 4);

        // pair combine: 1 exp
        const float pm = fmaxf(d0, d1);
        const float ee = __expf(-fabsf(d0 - d1));
        const bool g = d0 >= d1;
        const float v0x = __uint_as_float(c0.y << 16), v0y = __uint_as_float(c0.y & 0xffff0000u);
        const float v1x = __uint_as_float(c1.y << 16), v1y = __uint_as_float(c1.y & 0xffff0000u);
        const float sp  = 1.f + ee;
        const float ovx = fmaf(ee, g ? v1x : v0x, g ? v0x : v1x);
        const float ovy = fmaf(ee, g ? v1y : v0y, g ? v0y : v1y);

        // online merge: 1 exp
        const float dd = pm - m;
        const float em = __expf(-fabsf(dd));
        const bool nm = dd > 0.f;
        const float so = nm ? em : 1.f;
        const float sn = nm ? 1.f : em;
        m = nm ? pm : m;
        s  = fmaf(s,  so, sp  * sn);
        ox = fmaf(ox, so, ovx * sn);
        oy = fmaf(oy, so, ovy * sn);
    }
    if (i < deg) {  // odd tail
        const uint2 c0 = kvA;
        float d0 = qx * __uint_as_float(c0.x << 16) + qy * __uint_as_float(c0.x & 0xffff0000u);
        d0 += __shfl_xor(d0, 1);
        d0 += __shfl_xor(d0, 2);
        d0 += __shfl_xor(d0, 4);
        const float vx = __uint_as_float(c0.y << 16), vy = __uint_as_float(c0.y & 0xffff0000u);
        const float dd = d0 - m;
        const float em = __expf(-fabsf(dd));
        const bool nm = dd > 0.f;
        const float so = nm ? em : 1.f;
        const float pp = nm ? 1.f : em;
        m = nm ? d0 : m;
        s  = fmaf(s,  so, pp);
        ox = fmaf(ox, so, pp * vx);
        oy = fmaf(oy, so, pp * vy);
    }
    const float inv = 1.f / (s + 1e-12f);
    ushort2 ob = { f2b(ox * inv), f2b(oy * inv) };
    *(ushort2*)(accumb + (size_t)n * HIDDEN + lane * 2) = ob;
}

// ---- output projection: non-swapped mfma, pipelined B loads ----
__global__ __launch_bounds__(256)
void outproj_mfma(const unsigned short* __restrict__ accumb, const unsigned short* __restrict__ Po,
                  const float* __restrict__ bo, float* __restrict__ out)
{
    const int band = blockIdx.x * 4 + (threadIdx.x >> 6);
    if (band >= 3125) return;
    const int lane = threadIdx.x & 63;
    const int row0 = band * 16;
    const int ar = lane & 15, kg = lane >> 4;

    const unsigned short* ab = accumb + (size_t)(row0 + ar) * 128 + kg * 8;
    const bf16x8 a0 = *(const bf16x8*)(ab);
    const bf16x8 a1 = *(const bf16x8*)(ab + 32);
    const bf16x8 a2 = *(const bf16x8*)(ab + 64);
    const bf16x8 a3 = *(const bf16x8*)(ab + 96);

    const unsigned short* wp = Po + lane * 8;
    bf16x8 nb0 = *(const bf16x8*)(wp);
    bf16x8 nb1 = *(const bf16x8*)(wp + 512);
    bf16x8 nb2 = *(const bf16x8*)(wp + 1024);
    bf16x8 nb3 = *(const bf16x8*)(wp + 1536);

#pragma unroll
    for (int t = 0; t < 8; ++t) {
        const bf16x8 b0 = nb0, b1 = nb1, b2 = nb2, b3 = nb3;
        if (t < 7) {
            const unsigned short* nw = wp + (size_t)(t + 1) * 2048;
            nb0 = *(const bf16x8*)(nw);
            nb1 = *(const bf16x8*)(nw + 512);
            nb2 = *(const bf16x8*)(nw + 1024);
            nb3 = *(const bf16x8*)(nw + 1536);
        }
        f32x4 acc = {0.f, 0.f, 0.f, 0.f};
        acc = __builtin_amdgcn_mfma_f32_16x16x32_bf16(a0, b0, acc, 0, 0, 0);
        acc = __builtin_amdgcn_mfma_f32_16x16x32_bf16(a1, b1, acc, 0, 0, 0);
        acc = __builtin_amdgcn_mfma_f32_16x16x32_bf16(a2, b2, acc, 0, 0, 0);
        acc = __builtin_amdgcn_mfma_f32_16x16x32_bf16(a3, b3, acc, 0, 0, 0);

        const int colin = t * 16 + ar;
        const float bsc = bo[colin];
#pragma unroll
        for (int j = 0; j < 4; ++j)
            out[(size_t)(row0 + kg * 4 + j) * 128 + colin] = acc[j] + bsc;
    }
}

extern "C" void kernel_launch(void* const* d_in, const int* in_sizes, int n_in,
                              void* d_out, int out_size, void* d_ws, size_t ws_size,
                              hipStream_t stream) {
    const float* x  = (const float*)d_in[0];
    const int*   ei = (const int*)d_in[1];      // (2, E) int32: [0]=src, [1]=dst
    const int*   src = ei;
    const int*   dst = ei + NEDGES;
    const float* Wq = (const float*)d_in[3];
    const float* bq = (const float*)d_in[4];
    const float* Wk = (const float*)d_in[5];
    const float* bk = (const float*)d_in[6];
    const float* Wv = (const float*)d_in[7];
    const float* bv = (const float*)d_in[8];
    const float* Wo = (const float*)d_in[9];
    const float* bo = (const float*)d_in[10];
    float* out = (float*)d_out;

    // workspace layout (all offsets 16B-aligned)
    char* ws = (char*)d_ws;
    size_t off = 0;
    const size_t sz_nhb = (size_t)NNODES * HIDDEN * sizeof(unsigned short); // 12.8 MB
    unsigned short* Qb     = (unsigned short*)(ws + off); off += sz_nhb;
    unsigned short* KVb    = (unsigned short*)(ws + off); off += 2 * sz_nhb;
    unsigned short* accumb = (unsigned short*)(ws + off); off += sz_nhb;
    unsigned short* Pqkv   = (unsigned short*)(ws + off); off += 96 * 512 * sizeof(unsigned short);
    unsigned short* Po     = (unsigned short*)(ws + off); off += 32 * 512 * sizeof(unsigned short);
    int*            cnt    = (int*)(ws + off);            off += (size_t)NNODES * sizeof(int);
    int*            bucket = (int*)(ws + off);            off += (size_t)NNODES * CAP * sizeof(int);

    hipMemsetAsync(cnt, 0, (size_t)NNODES * sizeof(int), stream);

    pack_w<<<32, 256, 0, stream>>>(Wq, Wk, Wv, Wo, Pqkv, Po);

    scatter_kernel<<<NPART * SCAT_BPP, 256, 0, stream>>>(src, dst, cnt, bucket);

    qkv_mfma<<<(QKV_WAVES + 3) / 4, 256, 0, stream>>>(x, Pqkv, bq, bk, bv, Qb, KVb);

    fused_attn_kernel<<<(NNODES + 3) / 4, 256, 0, stream>>>(Qb, KVb, cnt, bucket, accumb);

    outproj_mfma<<<782, 256, 0, stream>>>(accumb, Po, bo, out);
}

// Round 10
// 139.193 us; speedup vs baseline: 1.1806x; 1.0623x over previous
//
#include <hip/hip_runtime.h>
#include <math.h>

#define NNODES 50000
#define NEDGES 800000
#define HIDDEN 128
#define NH 8
#define HD 16
#define CAP 64            // max in-degree; Binomial(8e5,1/5e4) max ~35, P(>=64) negligible
#define NPART 8           // dst partitions ~ XCDs
#define PART_SZ 6250      // 50000/8
#define SCAT_BPP 128      // blocks per partition
#define SCAT_BLOCKS (NPART * SCAT_BPP)   // 1024
#define QKV_WAVES 6250    // 3125 row-bands x 2 halves
#define QKV_BLOCKS 1563   // ceil(6250/4)

typedef __bf16 bf16x8 __attribute__((ext_vector_type(8)));
typedef float  f32x4  __attribute__((ext_vector_type(4)));

// RNE float -> bf16 bits
__device__ inline unsigned short f2b(float f) {
    unsigned u = __float_as_uint(f);
    unsigned r = (u + 0x7fffu + ((u >> 16) & 1u)) >> 16;
    return (unsigned short)r;
}

// load 8 consecutive fp32 -> one bf16x8 MFMA fragment
__device__ inline bf16x8 ld_a8(const float* __restrict__ p) {
    float4 a = *(const float4*)p;
    float4 b = *(const float4*)(p + 4);
    bf16x8 r;
    r[0] = (__bf16)a.x; r[1] = (__bf16)a.y; r[2] = (__bf16)a.z; r[3] = (__bf16)a.w;
    r[4] = (__bf16)b.x; r[5] = (__bf16)b.y; r[6] = (__bf16)b.z; r[7] = (__bf16)b.w;
    return r;
}

// ---- pack weights into MFMA fragment order + zero cnt (fat) ----
// pack blocks 0..31: slot s (0..95: qkv, 96..127: Wo): P[s*512 + lane*8 + j] =
//   W[colin*128 + c*32 + (lane>>4)*8 + j],  colin = ct*16 + (lane&15), s = ct*4+c
// blocks 32..80: zero the 50000-int cnt array (12500 int4 stores)
__global__ __launch_bounds__(256)
void pack_init(const float* __restrict__ Wq, const float* __restrict__ Wk,
               const float* __restrict__ Wv, const float* __restrict__ Wo,
               unsigned short* __restrict__ Pqkv, unsigned short* __restrict__ Po,
               int* __restrict__ cnt)
{
    if (blockIdx.x >= 32) {
        const int idx = (blockIdx.x - 32) * 256 + threadIdx.x;   // int4 index
        if (idx < NNODES / 4) ((int4*)cnt)[idx] = make_int4(0, 0, 0, 0);
        return;
    }
    const int s = blockIdx.x * 4 + (threadIdx.x >> 6);   // 0..127
    const int lane = threadIdx.x & 63;
    const float* W; unsigned short* P; int ct, c;
    if (s < 96) { ct = s >> 2; c = s & 3;
        W = (ct < 8) ? Wq : (ct < 16) ? Wk : Wv;
        P = Pqkv + (size_t)s * 512;
        ct &= 7;
    } else { int t = s - 96; ct = t >> 2; c = t & 3; W = Wo; P = Po + (size_t)t * 512; }
    const int colin = ct * 16 + (lane & 15);
    const int k0 = c * 32 + (lane >> 4) * 8;
    const float* sp = W + (size_t)colin * 128 + k0;
    unsigned short v[8];
#pragma unroll
    for (int j = 0; j < 8; ++j) v[j] = f2b(sp[j]);
    uint4 o;
    o.x = (unsigned)v[0] | ((unsigned)v[1] << 16);
    o.y = (unsigned)v[2] | ((unsigned)v[3] << 16);
    o.z = (unsigned)v[4] | ((unsigned)v[5] << 16);
    o.w = (unsigned)v[6] | ((unsigned)v[7] << 16);
    *(uint4*)(P + lane * 8) = o;
}

// ---- Fat kernel: QKV projection + XCD-partitioned edge bucketing ----
// qkv blocks (< QKV_BLOCKS): non-swapped mfma(x,W), pipelined B loads.
// lane (ar=lane&15, kg=lane>>4) holds C[row0+kg*4+j][ct*16+ar].
// KVb pairwise layout: K[2l..2l+1] at n*256+4l, V[2l..2l+1] at n*256+4l+2.
// scatter blocks (>= QKV_BLOCKS): partition p owns dst in [p*PART_SZ,..+PART_SZ);
// grid-strides full edge list -> bucket slice stays in one XCD's L2.
__global__ __launch_bounds__(256)
void qkv_scatter(const float* __restrict__ x, const unsigned short* __restrict__ Pqkv,
                 const float* __restrict__ bq, const float* __restrict__ bk,
                 const float* __restrict__ bv,
                 const int* __restrict__ src, const int* __restrict__ dst,
                 unsigned short* __restrict__ Qb, unsigned short* __restrict__ KVb,
                 int* __restrict__ cnt, int* __restrict__ bucket)
{
    if (blockIdx.x >= QKV_BLOCKS) {
        const int sb = blockIdx.x - QKV_BLOCKS;
        const int part = sb & (NPART - 1);
        const int blk  = sb >> 3;              // 0..SCAT_BPP-1
        const int lo = part * PART_SZ, hi = lo + PART_SZ;
        for (int e = blk * 256 + threadIdx.x; e < NEDGES; e += SCAT_BPP * 256) {
            const int d = dst[e];
            if (d >= lo && d < hi) {
                const int pos = atomicAdd(&cnt[d], 1);
                if (pos < CAP) bucket[d * CAP + pos] = src[e];
            }
        }
        return;
    }

    const int w = blockIdx.x * 4 + (threadIdx.x >> 6);
    if (w >= QKV_WAVES) return;
    const int lane = threadIdx.x & 63;
    const int band = w >> 1, half = w & 1;
    const int row0 = band * 16;
    const int ar = lane & 15, kg = lane >> 4;

    const float* ap = x + (size_t)(row0 + ar) * 128 + kg * 8;
    const bf16x8 a0 = ld_a8(ap);
    const bf16x8 a1 = ld_a8(ap + 32);
    const bf16x8 a2 = ld_a8(ap + 64);
    const bf16x8 a3 = ld_a8(ap + 96);

    const unsigned short* wp = Pqkv + (size_t)(half * 48) * 512 + lane * 8;
    // prefetch tile 0's B fragments
    bf16x8 nb0 = *(const bf16x8*)(wp);
    bf16x8 nb1 = *(const bf16x8*)(wp + 512);
    bf16x8 nb2 = *(const bf16x8*)(wp + 1024);
    bf16x8 nb3 = *(const bf16x8*)(wp + 1536);

#pragma unroll
    for (int t = 0; t < 12; ++t) {
        const bf16x8 b0 = nb0, b1 = nb1, b2 = nb2, b3 = nb3;
        if (t < 11) {
            const unsigned short* nw = wp + (size_t)(t + 1) * 2048;
            nb0 = *(const bf16x8*)(nw);
            nb1 = *(const bf16x8*)(nw + 512);
            nb2 = *(const bf16x8*)(nw + 1024);
            nb3 = *(const bf16x8*)(nw + 1536);
        }
        f32x4 acc = {0.f, 0.f, 0.f, 0.f};
        acc = __builtin_amdgcn_mfma_f32_16x16x32_bf16(a0, b0, acc, 0, 0, 0);
        acc = __builtin_amdgcn_mfma_f32_16x16x32_bf16(a1, b1, acc, 0, 0, 0);
        acc = __builtin_amdgcn_mfma_f32_16x16x32_bf16(a2, b2, acc, 0, 0, 0);
        acc = __builtin_amdgcn_mfma_f32_16x16x32_bf16(a3, b3, acc, 0, 0, 0);

        const int ct = half * 12 + t;
        const int sel = ct >> 3;              // 0=Q 1=K 2=V
        const int colin = (ct & 7) * 16 + ar;
        if (sel == 0) {
            const float bsc = bq[colin];
#pragma unroll
            for (int j = 0; j < 4; ++j)
                Qb[(size_t)(row0 + kg * 4 + j) * 128 + colin] = f2b(acc[j] + bsc);
        } else {
            const float bsc = (sel == 1) ? bk[colin] : bv[colin];
            const int koff = (sel == 2) ? 2 : 0;
            const int cbase = (colin >> 1) * 4 + (colin & 1) + koff;
#pragma unroll
            for (int j = 0; j < 4; ++j)
                KVb[(size_t)(row0 + kg * 4 + j) * 256 + cbase] = f2b(acc[j] + bsc);
        }
    }
}

// ---- Fused score + online softmax + aggregation, 1 wave / node ----
// pair-processed edges: two independent dot/reduce chains per iteration,
// pair-combined with 1 exp, then one online merge (1 exp) -> 1 exp/edge.
__global__ __launch_bounds__(256)
void fused_attn_kernel(const unsigned short* __restrict__ Qb,
                       const unsigned short* __restrict__ KVb,
                       const int* __restrict__ cnt, const int* __restrict__ bucket,
                       unsigned short* __restrict__ accumb)
{
    const int wave = threadIdx.x >> 6;
    const int lane = threadIdx.x & 63;
    const int n = blockIdx.x * 4 + wave;
    if (n >= NNODES) return;

    int deg = cnt[n];
    deg = deg > CAP ? CAP : deg;
    const int mysrc = (lane < deg) ? bucket[n * CAP + lane] : 0;

    const unsigned short* kvbase = KVb + lane * 4;

    // q pre-scaled by D^-0.5 so dot == score
    const unsigned qw = *(const unsigned*)(Qb + (size_t)n * HIDDEN + lane * 2);
    const float qx = __uint_as_float(qw << 16) * 0.25f;
    const float qy = __uint_as_float(qw & 0xffff0000u) * 0.25f;

    float m = -INFINITY, s = 0.f, ox = 0.f, oy = 0.f;

    // prefetch ring, depth 4
    uint2 kvA = make_uint2(0,0), kvB = kvA, kvC = kvA, kvD = kvA;
    if (deg > 0) kvA = *(const uint2*)(kvbase + ((size_t)__shfl(mysrc, 0) << 8));
    if (deg > 1) kvB = *(const uint2*)(kvbase + ((size_t)__shfl(mysrc, 1) << 8));
    if (deg > 2) kvC = *(const uint2*)(kvbase + ((size_t)__shfl(mysrc, 2) << 8));
    if (deg > 3) kvD = *(const uint2*)(kvbase + ((size_t)__shfl(mysrc, 3) << 8));

    int i = 0;
    for (; i + 2 <= deg; i += 2) {
        const uint2 c0 = kvA, c1 = kvB;
        kvA = kvC; kvB = kvD;
        if (i + 4 < deg) kvC = *(const uint2*)(kvbase + ((size_t)__shfl(mysrc, i + 4) << 8));
        if (i + 5 < deg) kvD = *(const uint2*)(kvbase + ((size_t)__shfl(mysrc, i + 5) << 8));

        // two independent score chains
        float d0 = qx * __uint_as_float(c0.x << 16) + qy * __uint_as_float(c0.x & 0xffff0000u);
        float d1 = qx * __uint_as_float(c1.x << 16) + qy * __uint_as_float(c1.x & 0xffff0000u);
        d0 += __shfl_xor(d0, 1);  d1 += __shfl_xor(d1, 1);
        d0 += __shfl_xor(d0, 2);  d1 += __shfl_xor(d1, 2);
        d0 += __shfl_xor(d0, 4);  d1 += __shfl_xor(d1, 4);

        // pair combine: 1 exp
        const float pm = fmaxf(d0, d1);
        const float ee = __expf(-fabsf(d0 - d1));
        const bool g = d0 >= d1;
        const float v0x = __uint_as_float(c0.y << 16), v0y = __uint_as_float(c0.y & 0xffff0000u);
        const float v1x = __uint_as_float(c1.y << 16), v1y = __uint_as_float(c1.y & 0xffff0000u);
        const float sp  = 1.f + ee;
        const float ovx = fmaf(ee, g ? v1x : v0x, g ? v0x : v1x);
        const float ovy = fmaf(ee, g ? v1y : v0y, g ? v0y : v1y);

        // online merge: 1 exp
        const float dd = pm - m;
        const float em = __expf(-fabsf(dd));
        const bool nm = dd > 0.f;
        const float so = nm ? em : 1.f;
        const float sn = nm ? 1.f : em;
        m = nm ? pm : m;
        s  = fmaf(s,  so, sp  * sn);
        ox = fmaf(ox, so, ovx * sn);
        oy = fmaf(oy, so, ovy * sn);
    }
    if (i < deg) {  // odd tail
        const uint2 c0 = kvA;
        float d0 = qx * __uint_as_float(c0.x << 16) + qy * __uint_as_float(c0.x & 0xffff0000u);
        d0 += __shfl_xor(d0, 1);
        d0 += __shfl_xor(d0, 2);
        d0 += __shfl_xor(d0, 4);
        const float vx = __uint_as_float(c0.y << 16), vy = __uint_as_float(c0.y & 0xffff0000u);
        const float dd = d0 - m;
        const float em = __expf(-fabsf(dd));
        const bool nm = dd > 0.f;
        const float so = nm ? em : 1.f;
        const float pp = nm ? 1.f : em;
        m = nm ? d0 : m;
        s  = fmaf(s,  so, pp);
        ox = fmaf(ox, so, pp * vx);
        oy = fmaf(oy, so, pp * vy);
    }
    const float inv = 1.f / (s + 1e-12f);
    ushort2 ob = { f2b(ox * inv), f2b(oy * inv) };
    *(ushort2*)(accumb + (size_t)n * HIDDEN + lane * 2) = ob;
}

// ---- output projection: non-swapped mfma, pipelined B loads ----
__global__ __launch_bounds__(256)
void outproj_mfma(const unsigned short* __restrict__ accumb, const unsigned short* __restrict__ Po,
                  const float* __restrict__ bo, float* __restrict__ out)
{
    const int band = blockIdx.x * 4 + (threadIdx.x >> 6);
    if (band >= 3125) return;
    const int lane = threadIdx.x & 63;
    const int row0 = band * 16;
    const int ar = lane & 15, kg = lane >> 4;

    const unsigned short* ab = accumb + (size_t)(row0 + ar) * 128 + kg * 8;
    const bf16x8 a0 = *(const bf16x8*)(ab);
    const bf16x8 a1 = *(const bf16x8*)(ab + 32);
    const bf16x8 a2 = *(const bf16x8*)(ab + 64);
    const bf16x8 a3 = *(const bf16x8*)(ab + 96);

    const unsigned short* wp = Po + lane * 8;
    bf16x8 nb0 = *(const bf16x8*)(wp);
    bf16x8 nb1 = *(const bf16x8*)(wp + 512);
    bf16x8 nb2 = *(const bf16x8*)(wp + 1024);
    bf16x8 nb3 = *(const bf16x8*)(wp + 1536);

#pragma unroll
    for (int t = 0; t < 8; ++t) {
        const bf16x8 b0 = nb0, b1 = nb1, b2 = nb2, b3 = nb3;
        if (t < 7) {
            const unsigned short* nw = wp + (size_t)(t + 1) * 2048;
            nb0 = *(const bf16x8*)(nw);
            nb1 = *(const bf16x8*)(nw + 512);
            nb2 = *(const bf16x8*)(nw + 1024);
            nb3 = *(const bf16x8*)(nw + 1536);
        }
        f32x4 acc = {0.f, 0.f, 0.f, 0.f};
        acc = __builtin_amdgcn_mfma_f32_16x16x32_bf16(a0, b0, acc, 0, 0, 0);
        acc = __builtin_amdgcn_mfma_f32_16x16x32_bf16(a1, b1, acc, 0, 0, 0);
        acc = __builtin_amdgcn_mfma_f32_16x16x32_bf16(a2, b2, acc, 0, 0, 0);
        acc = __builtin_amdgcn_mfma_f32_16x16x32_bf16(a3, b3, acc, 0, 0, 0);

        const int colin = t * 16 + ar;
        const float bsc = bo[colin];
#pragma unroll
        for (int j = 0; j < 4; ++j)
            out[(size_t)(row0 + kg * 4 + j) * 128 + colin] = acc[j] + bsc;
    }
}

extern "C" void kernel_launch(void* const* d_in, const int* in_sizes, int n_in,
                              void* d_out, int out_size, void* d_ws, size_t ws_size,
                              hipStream_t stream) {
    const float* x  = (const float*)d_in[0];
    const int*   ei = (const int*)d_in[1];      // (2, E) int32: [0]=src, [1]=dst
    const int*   src = ei;
    const int*   dst = ei + NEDGES;
    const float* Wq = (const float*)d_in[3];
    const float* bq = (const float*)d_in[4];
    const float* Wk = (const float*)d_in[5];
    const float* bk = (const float*)d_in[6];
    const float* Wv = (const float*)d_in[7];
    const float* bv = (const float*)d_in[8];
    const float* Wo = (const float*)d_in[9];
    const float* bo = (const float*)d_in[10];
    float* out = (float*)d_out;

    // workspace layout (all offsets 16B-aligned)
    char* ws = (char*)d_ws;
    size_t off = 0;
    const size_t sz_nhb = (size_t)NNODES * HIDDEN * sizeof(unsigned short); // 12.8 MB
    unsigned short* Qb     = (unsigned short*)(ws + off); off += sz_nhb;
    unsigned short* KVb    = (unsigned short*)(ws + off); off += 2 * sz_nhb;
    unsigned short* accumb = (unsigned short*)(ws + off); off += sz_nhb;
    unsigned short* Pqkv   = (unsigned short*)(ws + off); off += 96 * 512 * sizeof(unsigned short);
    unsigned short* Po     = (unsigned short*)(ws + off); off += 32 * 512 * sizeof(unsigned short);
    int*            cnt    = (int*)(ws + off);            off += (size_t)NNODES * sizeof(int);
    int*            bucket = (int*)(ws + off);            off += (size_t)NNODES * CAP * sizeof(int);

    // 32 pack blocks + 49 cnt-zero blocks
    pack_init<<<81, 256, 0, stream>>>(Wq, Wk, Wv, Wo, Pqkv, Po, cnt);

    // fat: 1563 qkv blocks + 1024 scatter blocks, co-resident
    qkv_scatter<<<QKV_BLOCKS + SCAT_BLOCKS, 256, 0, stream>>>(
        x, Pqkv, bq, bk, bv, src, dst, Qb, KVb, cnt, bucket);

    fused_attn_kernel<<<(NNODES + 3) / 4, 256, 0, stream>>>(Qb, KVb, cnt, bucket, accumb);

    outproj_mfma<<<782, 256, 0, stream>>>(accumb, Po, bo, out);
}

// Round 11
// 137.595 us; speedup vs baseline: 1.1943x; 1.0116x over previous
//
#include <hip/hip_runtime.h>
#include <math.h>

#define NNODES 50000
#define NEDGES 800000
#define HIDDEN 128
#define NH 8
#define HD 16
#define CAP 64            // max in-degree; Binomial(8e5,1/5e4) max ~35, P(>=64) negligible
#define NPART 8           // dst partitions ~ XCDs
#define PART_SZ 6250      // 50000/8
#define SCAT_BPP 128      // blocks per partition
#define SCAT_BLOCKS (NPART * SCAT_BPP)   // 1024
#define QKV_BLOCKS 782    // ceil(3125 bands / 4 waves)

typedef __bf16 bf16x8 __attribute__((ext_vector_type(8)));
typedef float  f32x4  __attribute__((ext_vector_type(4)));

// RNE float -> bf16 bits
__device__ inline unsigned short f2b(float f) {
    unsigned u = __float_as_uint(f);
    unsigned r = (u + 0x7fffu + ((u >> 16) & 1u)) >> 16;
    return (unsigned short)r;
}

// load 8 consecutive fp32 -> one bf16x8 MFMA fragment
__device__ inline bf16x8 ld_a8(const float* __restrict__ p) {
    float4 a = *(const float4*)p;
    float4 b = *(const float4*)(p + 4);
    bf16x8 r;
    r[0] = (__bf16)a.x; r[1] = (__bf16)a.y; r[2] = (__bf16)a.z; r[3] = (__bf16)a.w;
    r[4] = (__bf16)b.x; r[5] = (__bf16)b.y; r[6] = (__bf16)b.z; r[7] = (__bf16)b.w;
    return r;
}

// unpack 8 bf16 (4 dwords) -> 8 fp32
__device__ inline void up8(const uint4 u, float* f) {
    f[0] = __uint_as_float(u.x << 16); f[1] = __uint_as_float(u.x & 0xffff0000u);
    f[2] = __uint_as_float(u.y << 16); f[3] = __uint_as_float(u.y & 0xffff0000u);
    f[4] = __uint_as_float(u.z << 16); f[5] = __uint_as_float(u.z & 0xffff0000u);
    f[6] = __uint_as_float(u.w << 16); f[7] = __uint_as_float(u.w & 0xffff0000u);
}

// ---- pack weights into MFMA fragment order + zero cnt (fat) ----
__global__ __launch_bounds__(256)
void pack_init(const float* __restrict__ Wq, const float* __restrict__ Wk,
               const float* __restrict__ Wv, const float* __restrict__ Wo,
               unsigned short* __restrict__ Pqkv, unsigned short* __restrict__ Po,
               int* __restrict__ cnt)
{
    if (blockIdx.x >= 32) {
        const int idx = (blockIdx.x - 32) * 256 + threadIdx.x;   // int4 index
        if (idx < NNODES / 4) ((int4*)cnt)[idx] = make_int4(0, 0, 0, 0);
        return;
    }
    const int s = blockIdx.x * 4 + (threadIdx.x >> 6);   // 0..127
    const int lane = threadIdx.x & 63;
    const float* W; unsigned short* P; int ct, c;
    if (s < 96) { ct = s >> 2; c = s & 3;
        W = (ct < 8) ? Wq : (ct < 16) ? Wk : Wv;
        P = Pqkv + (size_t)s * 512;
        ct &= 7;
    } else { int t = s - 96; ct = t >> 2; c = t & 3; W = Wo; P = Po + (size_t)t * 512; }
    const int colin = ct * 16 + (lane & 15);
    const int k0 = c * 32 + (lane >> 4) * 8;
    const float* sp = W + (size_t)colin * 128 + k0;
    unsigned short v[8];
#pragma unroll
    for (int j = 0; j < 8; ++j) v[j] = f2b(sp[j]);
    uint4 o;
    o.x = (unsigned)v[0] | ((unsigned)v[1] << 16);
    o.y = (unsigned)v[2] | ((unsigned)v[3] << 16);
    o.z = (unsigned)v[4] | ((unsigned)v[5] << 16);
    o.w = (unsigned)v[6] | ((unsigned)v[7] << 16);
    *(uint4*)(P + lane * 8) = o;
}

// ---- Fat kernel: QKV projection (1 wave per band, 24 tiles) + bucketing ----
// lane (ar=lane&15, kg=lane>>4) holds C[row0+kg*4+j][ct*16+ar].
// KVb row layout: [K 128 bf16 | V 128 bf16] = 512B per node.
__global__ __launch_bounds__(256)
void qkv_scatter(const float* __restrict__ x, const unsigned short* __restrict__ Pqkv,
                 const float* __restrict__ bq, const float* __restrict__ bk,
                 const float* __restrict__ bv,
                 const int* __restrict__ src, const int* __restrict__ dst,
                 unsigned short* __restrict__ Qb, unsigned short* __restrict__ KVb,
                 int* __restrict__ cnt, int* __restrict__ bucket)
{
    if (blockIdx.x >= QKV_BLOCKS) {
        const int sb = blockIdx.x - QKV_BLOCKS;
        const int part = sb & (NPART - 1);
        const int blk  = sb >> 3;              // 0..SCAT_BPP-1
        const int lo = part * PART_SZ, hi = lo + PART_SZ;
        for (int e = blk * 256 + threadIdx.x; e < NEDGES; e += SCAT_BPP * 256) {
            const int d = dst[e];
            if (d >= lo && d < hi) {
                const int pos = atomicAdd(&cnt[d], 1);
                if (pos < CAP) bucket[d * CAP + pos] = src[e];
            }
        }
        return;
    }

    const int w = blockIdx.x * 4 + (threadIdx.x >> 6);   // band 0..3124
    if (w >= 3125) return;
    const int lane = threadIdx.x & 63;
    const int row0 = w * 16;
    const int ar = lane & 15, kg = lane >> 4;

    const float* ap = x + (size_t)(row0 + ar) * 128 + kg * 8;
    const bf16x8 a0 = ld_a8(ap);
    const bf16x8 a1 = ld_a8(ap + 32);
    const bf16x8 a2 = ld_a8(ap + 64);
    const bf16x8 a3 = ld_a8(ap + 96);

    const unsigned short* wp = Pqkv + lane * 8;
    // prefetch tile 0's B fragments
    bf16x8 nb0 = *(const bf16x8*)(wp);
    bf16x8 nb1 = *(const bf16x8*)(wp + 512);
    bf16x8 nb2 = *(const bf16x8*)(wp + 1024);
    bf16x8 nb3 = *(const bf16x8*)(wp + 1536);

#pragma unroll
    for (int t = 0; t < 24; ++t) {
        const bf16x8 b0 = nb0, b1 = nb1, b2 = nb2, b3 = nb3;
        if (t < 23) {
            const unsigned short* nw = wp + (size_t)(t + 1) * 2048;
            nb0 = *(const bf16x8*)(nw);
            nb1 = *(const bf16x8*)(nw + 512);
            nb2 = *(const bf16x8*)(nw + 1024);
            nb3 = *(const bf16x8*)(nw + 1536);
        }
        f32x4 acc = {0.f, 0.f, 0.f, 0.f};
        acc = __builtin_amdgcn_mfma_f32_16x16x32_bf16(a0, b0, acc, 0, 0, 0);
        acc = __builtin_amdgcn_mfma_f32_16x16x32_bf16(a1, b1, acc, 0, 0, 0);
        acc = __builtin_amdgcn_mfma_f32_16x16x32_bf16(a2, b2, acc, 0, 0, 0);
        acc = __builtin_amdgcn_mfma_f32_16x16x32_bf16(a3, b3, acc, 0, 0, 0);

        const int sel = t >> 3;               // 0=Q 1=K 2=V
        const int colin = (t & 7) * 16 + ar;
        if (sel == 0) {
            const float bsc = bq[colin];
#pragma unroll
            for (int j = 0; j < 4; ++j)
                Qb[(size_t)(row0 + kg * 4 + j) * 128 + colin] = f2b(acc[j] + bsc);
        } else if (sel == 1) {
            const float bsc = bk[colin];
#pragma unroll
            for (int j = 0; j < 4; ++j)
                KVb[(size_t)(row0 + kg * 4 + j) * 256 + colin] = f2b(acc[j] + bsc);
        } else {
            const float bsc = bv[colin];
#pragma unroll
            for (int j = 0; j < 4; ++j)
                KVb[(size_t)(row0 + kg * 4 + j) * 256 + 128 + colin] = f2b(acc[j] + bsc);
        }
    }
}

// ---- Fused attn: lane = (head h, edge slot); 8 edges in parallel ----
// Per lane: full 16-dim dot in registers (no per-edge cross-lane ops),
// per-lane online softmax, one butterfly merge (masks 1/2/4) at the end.
__global__ __launch_bounds__(256)
void fused_attn_kernel(const unsigned short* __restrict__ Qb,
                       const unsigned short* __restrict__ KVb,
                       const int* __restrict__ cnt, const int* __restrict__ bucket,
                       unsigned short* __restrict__ accumb)
{
    const int wave = threadIdx.x >> 6;
    const int lane = threadIdx.x & 63;
    const int n = blockIdx.x * 4 + wave;
    if (n >= NNODES) return;

    const int h = lane >> 3;      // head 0..7
    const int slot = lane & 7;    // edge slot 0..7

    int deg = cnt[n]; deg = deg > CAP ? CAP : deg;
    const int mysrc = (lane < deg) ? bucket[n * CAP + lane] : 0;

    // q[16] for this head, pre-scaled by D^-0.5
    float q[16];
    {
        const uint4* qp = (const uint4*)(Qb + (size_t)n * HIDDEN + h * 16);
        up8(qp[0], q); up8(qp[1], q + 8);
#pragma unroll
        for (int j = 0; j < 16; ++j) q[j] *= 0.25f;
    }

    float m = -1e30f, s = 0.f;
    float o[16];
#pragma unroll
    for (int j = 0; j < 16; ++j) o[j] = 0.f;

    const int nit = (deg + 7) >> 3;
    const uint4 zz = make_uint4(0, 0, 0, 0);
    uint4 k0 = zz, k1 = zz, v0 = zz, v1 = zz;
    if (slot < deg) {
        const int sid = __shfl(mysrc, slot);
        const uint4* kp = (const uint4*)(KVb + (size_t)sid * 256 + h * 16);
        k0 = kp[0]; k1 = kp[1];
        const uint4* vp = (const uint4*)(KVb + (size_t)sid * 256 + 128 + h * 16);
        v0 = vp[0]; v1 = vp[1];
    }

    for (int i = 0; i < nit; ++i) {
        uint4 nk0 = zz, nk1 = zz, nv0 = zz, nv1 = zz;
        const int nidx = i * 8 + 8 + slot;
        if (nidx < deg) {
            const int sid = __shfl(mysrc, nidx);
            const uint4* kp = (const uint4*)(KVb + (size_t)sid * 256 + h * 16);
            nk0 = kp[0]; nk1 = kp[1];
            const uint4* vp = (const uint4*)(KVb + (size_t)sid * 256 + 128 + h * 16);
            nv0 = vp[0]; nv1 = vp[1];
        }
        float kk[16], vv[16];
        up8(k0, kk); up8(k1, kk + 8);
        up8(v0, vv); up8(v1, vv + 8);

        float d0 = 0.f, d1 = 0.f, d2 = 0.f, d3 = 0.f;
#pragma unroll
        for (int j = 0; j < 16; j += 4) {
            d0 = fmaf(q[j],     kk[j],     d0);
            d1 = fmaf(q[j + 1], kk[j + 1], d1);
            d2 = fmaf(q[j + 2], kk[j + 2], d2);
            d3 = fmaf(q[j + 3], kk[j + 3], d3);
        }
        float score = (d0 + d1) + (d2 + d3);
        if (i * 8 + slot >= deg) score = -2e30f;   // inactive slot

        const float dd = score - m;
        const float em = __expf(-fabsf(dd));
        const bool nm = dd > 0.f;
        const float so = nm ? em : 1.f;
        const float pp = nm ? 1.f : em;
        m = nm ? score : m;
        s = fmaf(s, so, pp);
#pragma unroll
        for (int j = 0; j < 16; ++j)
            o[j] = fmaf(o[j], so, pp * vv[j]);

        k0 = nk0; k1 = nk1; v0 = nv0; v1 = nv1;
    }

    // butterfly merge across the 8 slots of each head (lane low-3 bits)
#pragma unroll
    for (int mask = 1; mask <= 4; mask <<= 1) {
        const float om = __shfl_xor(m, mask);
        const float dd = om - m;
        const float em = __expf(-fabsf(dd));
        const bool nm = dd > 0.f;
        const float so = nm ? em : 1.f;   // scale mine
        const float oo = nm ? 1.f : em;   // scale other's
        m = nm ? om : m;
        const float os = __shfl_xor(s, mask);
        s = fmaf(s, so, os * oo);
#pragma unroll
        for (int j = 0; j < 16; ++j) {
            const float oj = __shfl_xor(o[j], mask);
            o[j] = fmaf(o[j], so, oj * oo);
        }
    }

    if (slot == 0) {
        const float inv = 1.f / (s + 1e-12f);
        uint4 w0, w1;
        w0.x = (unsigned)f2b(o[0]  * inv) | ((unsigned)f2b(o[1]  * inv) << 16);
        w0.y = (unsigned)f2b(o[2]  * inv) | ((unsigned)f2b(o[3]  * inv) << 16);
        w0.z = (unsigned)f2b(o[4]  * inv) | ((unsigned)f2b(o[5]  * inv) << 16);
        w0.w = (unsigned)f2b(o[6]  * inv) | ((unsigned)f2b(o[7]  * inv) << 16);
        w1.x = (unsigned)f2b(o[8]  * inv) | ((unsigned)f2b(o[9]  * inv) << 16);
        w1.y = (unsigned)f2b(o[10] * inv) | ((unsigned)f2b(o[11] * inv) << 16);
        w1.z = (unsigned)f2b(o[12] * inv) | ((unsigned)f2b(o[13] * inv) << 16);
        w1.w = (unsigned)f2b(o[14] * inv) | ((unsigned)f2b(o[15] * inv) << 16);
        uint4* op = (uint4*)(accumb + (size_t)n * HIDDEN + h * 16);
        op[0] = w0; op[1] = w1;
    }
}

// ---- output projection: non-swapped mfma, pipelined B loads ----
__global__ __launch_bounds__(256)
void outproj_mfma(const unsigned short* __restrict__ accumb, const unsigned short* __restrict__ Po,
                  const float* __restrict__ bo, float* __restrict__ out)
{
    const int band = blockIdx.x * 4 + (threadIdx.x >> 6);
    if (band >= 3125) return;
    const int lane = threadIdx.x & 63;
    const int row0 = band * 16;
    const int ar = lane & 15, kg = lane >> 4;

    const unsigned short* ab = accumb + (size_t)(row0 + ar) * 128 + kg * 8;
    const bf16x8 a0 = *(const bf16x8*)(ab);
    const bf16x8 a1 = *(const bf16x8*)(ab + 32);
    const bf16x8 a2 = *(const bf16x8*)(ab + 64);
    const bf16x8 a3 = *(const bf16x8*)(ab + 96);

    const unsigned short* wp = Po + lane * 8;
    bf16x8 nb0 = *(const bf16x8*)(wp);
    bf16x8 nb1 = *(const bf16x8*)(wp + 512);
    bf16x8 nb2 = *(const bf16x8*)(wp + 1024);
    bf16x8 nb3 = *(const bf16x8*)(wp + 1536);

#pragma unroll
    for (int t = 0; t < 8; ++t) {
        const bf16x8 b0 = nb0, b1 = nb1, b2 = nb2, b3 = nb3;
        if (t < 7) {
            const unsigned short* nw = wp + (size_t)(t + 1) * 2048;
            nb0 = *(const bf16x8*)(nw);
            nb1 = *(const bf16x8*)(nw + 512);
            nb2 = *(const bf16x8*)(nw + 1024);
            nb3 = *(const bf16x8*)(nw + 1536);
        }
        f32x4 acc = {0.f, 0.f, 0.f, 0.f};
        acc = __builtin_amdgcn_mfma_f32_16x16x32_bf16(a0, b0, acc, 0, 0, 0);
        acc = __builtin_amdgcn_mfma_f32_16x16x32_bf16(a1, b1, acc, 0, 0, 0);
        acc = __builtin_amdgcn_mfma_f32_16x16x32_bf16(a2, b2, acc, 0, 0, 0);
        acc = __builtin_amdgcn_mfma_f32_16x16x32_bf16(a3, b3, acc, 0, 0, 0);

        const int colin = t * 16 + ar;
        const float bsc = bo[colin];
#pragma unroll
        for (int j = 0; j < 4; ++j)
            out[(size_t)(row0 + kg * 4 + j) * 128 + colin] = acc[j] + bsc;
    }
}

extern "C" void kernel_launch(void* const* d_in, const int* in_sizes, int n_in,
                              void* d_out, int out_size, void* d_ws, size_t ws_size,
                              hipStream_t stream) {
    const float* x  = (const float*)d_in[0];
    const int*   ei = (const int*)d_in[1];      // (2, E) int32: [0]=src, [1]=dst
    const int*   src = ei;
    const int*   dst = ei + NEDGES;
    const float* Wq = (const float*)d_in[3];
    const float* bq = (const float*)d_in[4];
    const float* Wk = (const float*)d_in[5];
    const float* bk = (const float*)d_in[6];
    const float* Wv = (const float*)d_in[7];
    const float* bv = (const float*)d_in[8];
    const float* Wo = (const float*)d_in[9];
    const float* bo = (const float*)d_in[10];
    float* out = (float*)d_out;

    // workspace layout (all offsets 16B-aligned)
    char* ws = (char*)d_ws;
    size_t off = 0;
    const size_t sz_nhb = (size_t)NNODES * HIDDEN * sizeof(unsigned short); // 12.8 MB
    unsigned short* Qb     = (unsigned short*)(ws + off); off += sz_nhb;
    unsigned short* KVb    = (unsigned short*)(ws + off); off += 2 * sz_nhb;
    unsigned short* accumb = (unsigned short*)(ws + off); off += sz_nhb;
    unsigned short* Pqkv   = (unsigned short*)(ws + off); off += 96 * 512 * sizeof(unsigned short);
    unsigned short* Po     = (unsigned short*)(ws + off); off += 32 * 512 * sizeof(unsigned short);
    int*            cnt    = (int*)(ws + off);            off += (size_t)NNODES * sizeof(int);
    int*            bucket = (int*)(ws + off);            off += (size_t)NNODES * CAP * sizeof(int);

    // 32 pack blocks + 49 cnt-zero blocks
    pack_init<<<81, 256, 0, stream>>>(Wq, Wk, Wv, Wo, Pqkv, Po, cnt);

    // fat: 782 qkv blocks + 1024 scatter blocks, co-resident
    qkv_scatter<<<QKV_BLOCKS + SCAT_BLOCKS, 256, 0, stream>>>(
        x, Pqkv, bq, bk, bv, src, dst, Qb, KVb, cnt, bucket);

    fused_attn_kernel<<<(NNODES + 3) / 4, 256, 0, stream>>>(Qb, KVb, cnt, bucket, accumb);

    outproj_mfma<<<782, 256, 0, stream>>>(accumb, Po, bo, out);
}